// Round 6
// baseline (291.050 us; speedup 1.0000x reference)
//
#include <hip/hip_runtime.h>
#include <hip/hip_bf16.h>

// PWC-Net correlation: out[b, dy*9+dx, y, x] =
//   (1/C) * sum_c first[b,c,y,x] * second[b,c, y+dy-4, x+dx-4]  (zero-padded)
// B=8, C=128, H=W=128.
//
// Round 6 (from R5's 104 us, WRITE=41.5MB i.e. no spill):
//  - `first` no longer staged in LDS: per-thread coalesced global->reg loads
//    (no cross-thread reuse -> LDS was wasted on it). LDS reads 4->3/channel.
//  - Manual x2 unroll with CONSTANT buffer pointers so alias analysis can
//    prove stage(k+1) DMAs don't alias compute(k) ds_reads (kills the
//    conservative vmcnt serialization of dynamic buf=k&1).
//  - Second staged as 2-row 1KB full-wave DMAs (8 per chunk, waves 0/1),
//    per-row half-wave fallback at y edges. OOB rows pre-zeroed once.
//  - XCD swizzle: 3 sibling blocks (same b,y0; dg=0,1,2) land on one XCD.

#define B  8
#define C  128
#define H  128
#define W  128
#define CC 4
#define YB 2
#define NTHR 192
#define NCHUNK (C / CC)        // 32
#define SROWS 4                // second rows per dy-group
#define CHSTRIDE (CC * H * W)  // 65536 floats per chunk step

typedef const void __attribute__((address_space(1)))* gvp;
typedef void __attribute__((address_space(3)))* lvp;

__device__ __forceinline__ void dma16(const float* g, float* l) {
    __builtin_amdgcn_global_load_lds((gvp)g, (lvp)l, 16, 0, 0);
}

__global__ __launch_bounds__(NTHR) __attribute__((amdgpu_waves_per_eu(4)))
void ModuleCorrelation_41970420416706_kernel(const float* __restrict__ first,
                                             const float* __restrict__ second,
                                             float* __restrict__ out) {
    __shared__ __align__(16) float sSec0[CC][SROWS][W];   // 8 KiB
    __shared__ __align__(16) float sSec1[CC][SROWS][W];   // 8 KiB

    // ---- XCD swizzle: siblings (same b,y0; member=dg) on one XCD ----
    const int p      = blockIdx.x;
    const int xcd    = p & 7;
    const int q      = p >> 3;
    const int member = q % 3;
    const int gq     = q / 3;
    const int g      = gq * 8 + xcd;        // [0,512)
    const int b   = g >> 6;
    const int y0  = (g & 63) * YB;
    const int d0  = member * 3;             // dy group base: 0, 3, 6

    const int t    = threadIdx.x;
    const int w    = t >> 6;                // wave = dy - d0, in [0,3)
    const int lane = t & 63;
    const int yi   = lane >> 5;
    const int x0   = (lane & 31) * 4;

    const float* firstB  = first  + (size_t)b * C * H * W;
    const float* secondB = second + (size_t)b * C * H * W;
    const int ybase = y0 + d0 - 4;

    // ---- pre-zero OOB rows of both buffers (chunk-invariant, done once) ----
    {
        const float4 z4 = make_float4(0.f, 0.f, 0.f, 0.f);
        for (int idx = t; idx < 2 * CC * SROWS * (W / 4); idx += NTHR) {  // 1024
            const int r2 = idx & 511;
            const int rr = (r2 >> 5) & 3;
            const int ys = ybase + rr;
            if (ys < 0 || ys >= H) {
                float4* base = (idx < 512) ? (float4*)&sSec0[0][0][0]
                                           : (float4*)&sSec1[0][0][0];
                base[r2] = z4;
            }
        }
    }

    // ---- async staging of second: 8 pair-DMAs (2 rows, 1 KB, full wave),
    //      waves 0 and 1 take 4 pairs each; per-row fallback at y edges ----
    auto stage = [&](float* sS, int chunk) {
        if (w >= 2) return;
        const int off = chunk * CHSTRIDE;
#pragma unroll
        for (int i = 0; i < 4; ++i) {
            const int pr  = w * 4 + i;          // pair 0..7
            const int c   = pr >> 1;
            const int rr0 = (pr & 1) * 2;
            const int ys0 = ybase + rr0;
            float* dst = sS + (c * SROWS + rr0) * W;
            if (ys0 >= 0 && ys0 + 1 < H) {      // both rows in range: 1 KB DMA
                dma16(secondB + off + (c * H + ys0) * W + lane * 4, dst);
            } else {
#pragma unroll
                for (int r = 0; r < 2; ++r) {
                    const int ys = ys0 + r;
                    if (ys >= 0 && ys < H && lane < 32)
                        dma16(secondB + off + (c * H + ys) * W + lane * 4,
                              dst + r * W);
                }
            }
        }
    };

    float acc[9][4];
#pragma unroll
    for (int dx = 0; dx < 9; ++dx)
#pragma unroll
        for (int j = 0; j < 4; ++j) acc[dx][j] = 0.f;

    const bool edgeL = (x0 == 0);
    const bool edgeR = (x0 == 124);
    const int offA = edgeL ? 0 : x0 - 4;    // clamped aligned read, masked below
    const int offC = edgeR ? x0 : x0 + 4;
    const int sOff = (yi + w) * W;          // rr = yi + w
    const float* fBase = firstB + (y0 + yi) * W + x0;

    auto compute = [&](const float* sS, int chunk) {
        const int off = chunk * CHSTRIDE;
#pragma unroll
        for (int c = 0; c < CC; ++c) {
            const float4 f  = *(const float4*)(fBase + off + c * (H * W));
            const float* sr = sS + c * (SROWS * W) + sOff;
            float4 A        = *(const float4*)(sr + offA);
            const float4 Bv = *(const float4*)(sr + x0);
            float4 Cv       = *(const float4*)(sr + offC);
            if (edgeL) { A.x = 0.f; A.y = 0.f; A.z = 0.f; A.w = 0.f; }
            if (edgeR) { Cv.x = 0.f; Cv.y = 0.f; Cv.z = 0.f; Cv.w = 0.f; }
            const float s[12] = {A.x,  A.y,  A.z,  A.w,
                                 Bv.x, Bv.y, Bv.z, Bv.w,
                                 Cv.x, Cv.y, Cv.z, Cv.w};
#pragma unroll
            for (int dx = 0; dx < 9; ++dx) {
                acc[dx][0] += f.x * s[dx + 0];
                acc[dx][1] += f.y * s[dx + 1];
                acc[dx][2] += f.z * s[dx + 2];
                acc[dx][3] += f.w * s[dx + 3];
            }
        }
    };

    float* s0 = &sSec0[0][0][0];
    float* s1 = &sSec1[0][0][0];

    stage(s0, 0);
    __syncthreads();                 // buf0 staged + zeros visible

    for (int k = 0; k < NCHUNK; k += 2) {
        stage(s1, k + 1);            // DMAs into s1 fly during compute(s0)
        compute(s0, k);
        __syncthreads();
        if (k + 2 < NCHUNK) stage(s0, k + 2);
        compute(s1, k + 1);
        __syncthreads();
    }

    // ---- epilogue ----
    const float scale = 1.0f / (float)C;
    const int dy = d0 + w;
    const int yOut = y0 + yi;
#pragma unroll
    for (int dx = 0; dx < 9; ++dx) {
        const int tc = dy * 9 + dx;
        float4 o;
        o.x = acc[dx][0] * scale;
        o.y = acc[dx][1] * scale;
        o.z = acc[dx][2] * scale;
        o.w = acc[dx][3] * scale;
        *(float4*)&out[((b * 81 + tc) * H + yOut) * W + x0] = o;
    }
}

extern "C" void kernel_launch(void* const* d_in, const int* in_sizes, int n_in,
                              void* d_out, int out_size, void* d_ws, size_t ws_size,
                              hipStream_t stream) {
    const float* first  = (const float*)d_in[0];
    const float* second = (const float*)d_in[1];
    float* out = (float*)d_out;

    dim3 grid(B * (H / YB) * 3);   // 1536 blocks = 6 per CU
    dim3 block(NTHR);              // 192 threads = 3 waves
    ModuleCorrelation_41970420416706_kernel<<<grid, block, 0, stream>>>(first, second, out);
}